// Round 14
// baseline (164.701 us; speedup 1.0000x reference)
//
#include <hip/hip_runtime.h>
#include <math.h>

// InfoNCE loss, K=3, SKIP=1, NEG=64
// z,c: (64,256,14,14) f32; Wk: (3,256,256) f32; neg_idx_k: (rows_k*64,) i32
// rows_k = 10752, 9856, 8960. row = (h*14+w)*64 + b.
//
// Pipeline (4 launches): prep (casts+transposes+zero), proj (M16 blocks,
// A-frags in regs, 16.9 KB LDS -> 8 blocks/CU), loss (R8 structure, TA
// floor ~51us), reduce.

typedef short bf16x8 __attribute__((ext_vector_type(8)));
typedef float f32x4 __attribute__((ext_vector_type(4)));

static __device__ __forceinline__ unsigned short f2bf(float f) {
    union { float f; unsigned int u; } x; x.f = f;
    unsigned int r = x.u + 0x7fffu + ((x.u >> 16) & 1u);   // RNE
    return (unsigned short)(r >> 16);
}

// float -> OCP e4m3fn (RNE, saturate to 448, subnormals handled)
static __device__ __forceinline__ unsigned char f2e4m3(float f) {
    union { float f; unsigned int u; } x; x.f = f;
    unsigned int s = (x.u >> 24) & 0x80u;
    float af = fabsf(f);
    if (af > 448.f) af = 448.f;
    x.f = af;
    unsigned int u = x.u;
    int e = (int)(u >> 23) - 127;
    unsigned int out;
    if (af == 0.f) {
        out = 0u;
    } else if (e < -6) {
        int mq = (int)rintf(af * 512.f);          // multiples of 2^-9
        out = (mq >= 8) ? 0x08u : (unsigned int)mq;
    } else {
        unsigned int r = u + 0x7FFFFu + ((u >> 20) & 1u);  // RNE, drop 20 bits
        int e2 = (int)(r >> 23) - 127;
        if (e2 > 8) out = 0x7Eu;                  // 448
        else out = (unsigned int)(((e2 + 7) << 3) | ((r >> 20) & 7u));
    }
    return (unsigned char)(s | out);
}

// async global->LDS DMA: per-lane global addr, dest = uniform base + lane*4
static __device__ __forceinline__ void gload_lds4(const void* g, void* l) {
    __builtin_amdgcn_global_load_lds(
        (const __attribute__((address_space(1))) void*)g,
        (__attribute__((address_space(3))) void*)l, 4, 0, 0);
}

// prep: blocks [0,768): Wk->bf16 (block0 also zeroes out[0]);
// [768,1792): z -> zt bf16 transposed; [1792,2816): c -> ct8 fp8 transposed.
__global__ __launch_bounds__(256)
void prep_kernel(const float* __restrict__ z, const float* __restrict__ c,
                 const float* __restrict__ Wk,
                 unsigned short* __restrict__ zt, unsigned char* __restrict__ ct8,
                 unsigned short* __restrict__ wkb, float* __restrict__ out) {
    __shared__ float tile[16][201];
    const int tid = threadIdx.x;
    int x = blockIdx.x;
    if (x < 768) {
        int i = x * 256 + tid;
        wkb[i] = f2bf(Wk[i]);
        if (x == 0 && tid == 0) out[0] = 0.f;
        return;
    }
    const bool isz = x < 1792;
    const int local = isz ? (x - 768) : (x - 1792);
    const float* src = isz ? z : c;
    const int b  = local & 63;
    const int c0 = (local >> 6) << 4;
    for (int i = tid; i < 16 * 196; i += 256) {
        int cc = i / 196;
        int hw = i - cc * 196;
        tile[cc][hw] = src[(size_t)((b << 8) + c0 + cc) * 196 + hw];
    }
    __syncthreads();
    if (isz) {
        for (int i = tid; i < 196 * 16; i += 256) {
            int hw = i >> 4, cc = i & 15;
            zt[(size_t)((hw << 6) + b) * 256 + c0 + cc] = f2bf(tile[cc][hw]);
        }
    } else {
        for (int i = tid; i < 196 * 16; i += 256) {
            int hw = i >> 4, cc = i & 15;
            ct8[(size_t)((hw << 6) + b) * 256 + c0 + cc] = f2e4m3(tile[cc][hw]);
        }
    }
}

// proj: ztwk8[k][row][o] = fp8(sum_c zt[zrow][c] * wk[k][o][c])
// Grid 1848 x 128 (2 waves). Unit = 16 rows of one k-segment
// (672/616/560 units). Stage A (16 rows x 512 B) once -> A-frags in 32
// VGPRs; then 8 iterations: stage 2 B-tiles (16 o-rows x 512 B each,
// reusing A's LDS), wave w computes o-tile 2*it+w (8 MFMA), direct fp8
// stores. LDS 16.9 KB -> 8 blocks/CU. QSTR 528: dword stride 132 = 4
// (mod 32) -> <=2-way (free) banking.
#define QSTR 528
__global__ __launch_bounds__(128, 4)
void proj_mfma_kernel(const unsigned short* __restrict__ zt,
                      const unsigned short* __restrict__ wkb,
                      unsigned char* __restrict__ ztwk8) {
    __shared__ __align__(16) unsigned char L[2 * 16 * QSTR];   // 16896 B
    const int tid = threadIdx.x;
    const int wv = tid >> 6, lane = tid & 63;
    const int m = lane & 15, kq = lane >> 4;

    const int u = blockIdx.x;
    int k, lt;
    if (u < 672)       { k = 0; lt = u; }
    else if (u < 1288) { k = 1; lt = u - 672; }
    else               { k = 2; lt = u - 1288; }
    const int row0  = lt << 4;
    const int zrow0 = row0 + (k + 2) * 896;            // h' = h + (k_idx+2)
    unsigned char* zo = ztwk8 + (size_t)k * 10752 * 256;
    const unsigned char* zsrc = (const unsigned char*)zt + (size_t)zrow0 * 512;
    const unsigned char* wsrc = (const unsigned char*)wkb + (size_t)k * 131072;

    // stage A: 16 rows x 512 B, coalesced b128
    for (int i = tid; i < 512; i += 128) {
        int sb = i << 4;
        int r = sb >> 9, off = sb & 511;
        *(int4*)(L + r * QSTR + off) = *(const int4*)(zsrc + sb);
    }
    __syncthreads();
    // A-frags -> regs (verified layout: row m, elements kq*8 + kk*32)
    bf16x8 af[8];
    #pragma unroll
    for (int kk = 0; kk < 8; ++kk)
        af[kk] = *(const bf16x8*)(L + m * QSTR + (kq << 4) + (kk << 6));
    __syncthreads();                                    // A slab now reusable

    for (int it = 0; it < 8; ++it) {
        for (int i = tid; i < 1024; i += 128) {         // stage 2 B-tiles
            int sb = i << 4;
            int t2 = sb >> 13;
            int rem = sb & 8191;
            int r = rem >> 9, off = rem & 511;
            *(int4*)(L + t2 * 16 * QSTR + r * QSTR + off) =
                *(const int4*)(wsrc + (size_t)(((it << 1) + t2) * 16 + r) * 512 + off);
        }
        __syncthreads();
        const int o0 = ((it << 1) + wv) << 4;
        const unsigned char* bb = L + wv * 16 * QSTR;
        f32x4 acc = {0.f, 0.f, 0.f, 0.f};
        #pragma unroll
        for (int kk = 0; kk < 8; ++kk) {
            bf16x8 bf = *(const bf16x8*)(bb + m * QSTR + (kq << 4) + (kk << 6));
            acc = __builtin_amdgcn_mfma_f32_16x16x32_bf16(af[kk], bf, acc, 0, 0, 0);
        }
        // D: col(o)=m, row(M)=kq*4+r (verified R8/R12 mapping)
        #pragma unroll
        for (int r = 0; r < 4; ++r)
            zo[(size_t)(row0 + (kq << 2) + r) * 256 + o0 + m] = f2e4m3(acc[r]);
        __syncthreads();
    }
}

// loss (R8-verbatim, TA-floor ~51us): one block (2 waves) per row. Wave0:
// DMA rows 0..32 + MFMA mt 0..2; wave1: DMA rows 33..64 + ctx + MFMA mt 3..4.
// Slots: 0 main, 1..64 negs, 65..79 pad (clamped). Cross-wave softmax.
#define ROWB 272
__global__ __launch_bounds__(128, 4)
void loss_mfma_kernel(const unsigned char* __restrict__ ct8,
                      const unsigned char* __restrict__ ztwk8,
                      const int* __restrict__ n0, const int* __restrict__ n1,
                      const int* __restrict__ n2, float* __restrict__ rowloss) {
    __shared__ __align__(16) unsigned char slab[65 * ROWB];   // 17680 B
    __shared__ __align__(16) unsigned char ctx_s[256];
    __shared__ float sred[2][2];
    const int tid = threadIdx.x;
    const int wv = tid >> 6, lane = tid & 63;
    const int m = lane & 15, kq = lane >> 4;

    int x = blockIdx.x;
    int k; const int* nb_base;
    if (x < 10752)      { k = 0; nb_base = n0; }
    else if (x < 20608) { k = 1; nb_base = n1; x -= 10752; }
    else                { k = 2; nb_base = n2; x -= 20608; }
    const int row = x;
    const unsigned char* flat8 = ztwk8 + (size_t)k * 10752 * 256;
    const float wk = (k == 0) ? (1.f / (3.f * 10752.f))
                   : (k == 1) ? (1.f / (3.f * 9856.f))
                              : (1.f / (3.f * 8960.f));
    const int rbase = (k == 0) ? 0 : (k == 1) ? 10752 : 20608;

    const int myidx = nb_base[((size_t)row << 6) + lane];

    if (wv == 0) {
        gload_lds4(flat8 + (size_t)row * 256 + (lane << 2), slab);          // j=0
        #pragma unroll
        for (int j = 1; j <= 32; ++j) {
            int idx = __builtin_amdgcn_readlane(myidx, j - 1);
            gload_lds4(flat8 + (size_t)idx * 256 + (lane << 2), slab + j * ROWB);
        }
    } else {
        gload_lds4(ct8 + (size_t)row * 256 + (lane << 2), ctx_s);
        #pragma unroll
        for (int j = 33; j <= 64; ++j) {
            int idx = __builtin_amdgcn_readlane(myidx, j - 1);
            gload_lds4(flat8 + (size_t)idx * 256 + (lane << 2), slab + j * ROWB);
        }
    }
    __syncthreads();   // drains vmcnt (DMA) for the whole block

    f32x4 acc[3] = {};
    const int mt0 = (wv == 0) ? 0 : 3;
    int soff[3];
    #pragma unroll
    for (int t = 0; t < 3; ++t) {
        int slot = ((mt0 + t) << 4) + m;
        if (slot > 64) slot = 64;
        soff[t] = slot * ROWB + (kq << 3);
    }
    const unsigned char* cp = ctx_s + (kq << 3);
    #pragma unroll
    for (int kk = 0; kk < 8; ++kk) {
        long long bfrag = *(const long long*)(cp + (kk << 5));
        #pragma unroll
        for (int t = 0; t < 3; ++t) {
            if (t < 2 || wv == 0) {
                long long af = *(const long long*)(slab + soff[t] + (kk << 5));
                acc[t] = __builtin_amdgcn_mfma_f32_16x16x32_fp8_fp8(af, bfrag, acc[t], 0, 0, 0);
            }
        }
    }

    float m_l = -1e30f;
    if (wv == 0) {
        #pragma unroll
        for (int t = 0; t < 3; ++t)
            #pragma unroll
            for (int r = 0; r < 4; ++r) m_l = fmaxf(m_l, acc[t][r]);
    } else {
        #pragma unroll
        for (int r = 0; r < 4; ++r) m_l = fmaxf(m_l, acc[0][r]);   // mt=3
        if (kq == 0) m_l = fmaxf(m_l, acc[1][0]);                  // slot 64
    }
    m_l = fmaxf(m_l, __shfl_xor(m_l, 16));
    m_l = fmaxf(m_l, __shfl_xor(m_l, 32));

    float s_l = 0.f;
    if (wv == 0) {
        #pragma unroll
        for (int t = 0; t < 3; ++t)
            #pragma unroll
            for (int r = 0; r < 4; ++r) s_l += __expf(acc[t][r] - m_l);
    } else {
        #pragma unroll
        for (int r = 0; r < 4; ++r) s_l += __expf(acc[0][r] - m_l);
        if (kq == 0) s_l += __expf(acc[1][0] - m_l);
    }
    s_l += __shfl_xor(s_l, 16);
    s_l += __shfl_xor(s_l, 32);

    float main_l = acc[0][0];   // valid at wv0 lane0 (slot 0)
    if (lane == 0) { sred[wv][0] = m_l; sred[wv][1] = s_l; }
    __syncthreads();
    if (tid == 0) {
        float m0 = sred[0][0], s0 = sred[0][1];
        float m1 = sred[1][0], s1 = sred[1][1];
        float mg = fmaxf(m0, m1);
        float sg = s0 * __expf(m0 - mg) + s1 * __expf(m1 - mg);
        float p0 = __expf(main_l - mg) / sg;
        rowloss[rbase + row] = -logf(p0 + 1e-11f) * wk;
    }
}

// Sum rowloss[0..29568) -> out[0] (out zeroed in prep)
__global__ __launch_bounds__(256)
void reduce_kernel(const float* __restrict__ rl, float* __restrict__ out) {
    float s = 0.f;
    const int stride = gridDim.x * blockDim.x;
    for (int i = blockIdx.x * blockDim.x + threadIdx.x; i < 29568; i += stride)
        s += rl[i];
    #pragma unroll
    for (int off = 32; off >= 1; off >>= 1) s += __shfl_xor(s, off);
    if ((threadIdx.x & 63) == 0) atomicAdd(out, s);
}

extern "C" void kernel_launch(void* const* d_in, const int* in_sizes, int n_in,
                              void* d_out, int out_size, void* d_ws, size_t ws_size,
                              hipStream_t stream) {
    const float* z  = (const float*)d_in[0];
    const float* c  = (const float*)d_in[1];
    const float* Wk = (const float*)d_in[2];
    const int* negs[3] = {(const int*)d_in[3], (const int*)d_in[4], (const int*)d_in[5]};
    float* out = (float*)d_out;

    char* p = (char*)d_ws;
    unsigned short* zt      = (unsigned short*)p;   p += (size_t)196 * 64 * 256 * 2;
    unsigned short* wkb     = (unsigned short*)p;   p += (size_t)3 * 65536 * 2;
    unsigned char*  ct8     = (unsigned char*)p;    p += (size_t)196 * 64 * 256;
    unsigned char*  ztwk8   = (unsigned char*)p;    p += (size_t)3 * 10752 * 256;
    float*          rowloss = (float*)p;

    prep_kernel<<<2816, 256, 0, stream>>>(z, c, Wk, zt, ct8, wkb, out);
    proj_mfma_kernel<<<1848, 128, 0, stream>>>(zt, wkb, ztwk8);
    loss_mfma_kernel<<<29568, 128, 0, stream>>>(ct8, ztwk8, negs[0], negs[1],
                                                negs[2], rowloss);
    reduce_kernel<<<32, 256, 0, stream>>>(rowloss, out);
}